// Round 6
// baseline (938.904 us; speedup 1.0000x reference)
//
#include <hip/hip_runtime.h>
#include <hip/hip_bf16.h>
#include <math.h>

#define NGRAPHS 256
#define PD_EPS 1e-6f
#define NCOLOR 16  // csr-build colors; color = bid & 15 (write-merged csr window,
                   // R4/R6). 16 colors -> 25KB LDS hist/cursor -> 6 blocks/CU.
#define CSHIFT 4
#define KB 96      // blocks per color per tower; 1536/tower = 6/CU LDS cap.
// R7: color = bid/KB scatters csr writes across XCDs. Keep bid&15.
// R9: fill/count serial-latency-bound -> 8-deep load pipeline (WIN).
// R10: exact-load agg (8-wide + 4/2/1 uniform tail) = proven-best agg; R11
// (fewer VMEM instrs) and R12 (node pairs) both failed: agg is latency x
// concurrency bound (~5 TB/s effective gather, L2-miss only 2.1 TB/s).
// R13: folded layer-3 GEMM into k_final (WIN, -105us).
// R14: kernel time ~420us vs 580 total -> ~160us is gaps/ramps/bufF. Fuse the
// two towers into EVERY kernel (2N-row global buffers; tower-2 csr entries
// pre-offset +N, csr window +E; segmented scan with block-aligned padding) and
// fuse agg<2>+pool via direct atomicAdd into pooled (bufF deleted).
// Dispatches 29 -> 12. R10 gather body untouched.

typedef __hip_bfloat16 bf16;
typedef unsigned short ushort_t;
typedef short bf8_t __attribute__((ext_vector_type(8)));   // 8 bf16 = 4 VGPRs
typedef float f4_t __attribute__((ext_vector_type(4)));    // MFMA accumulator

static __device__ __forceinline__ int wave_uniform(int v) {
  return __builtin_amdgcn_readfirstlane(v);
}
static __device__ __forceinline__ float b2f(bf16 h) { return __bfloat162float(h); }
static __device__ __forceinline__ bf16 f2b(float f) { return __float2bfloat16(f); }
static __device__ __forceinline__ short f2bbits(float f) {
  bf16 h = __float2bfloat16(f);
  return *reinterpret_cast<short*>(&h);
}

// ---------- pass1 (merged towers): per-(tower,color,block) degree hist ----------
__global__ __launch_bounds__(256) void k_count_part(const int* __restrict__ dst1,
                                                    const int* __restrict__ dst2,
                                                    ushort_t* __restrict__ partial1,
                                                    ushort_t* __restrict__ partial2,
                                                    int E, int n, int rng) {
  extern __shared__ int hist[];
  const int tbase = NCOLOR * KB;
  int tower = blockIdx.x >= tbase;
  int bid = blockIdx.x - (tower ? tbase : 0);
  const int* dst = tower ? dst2 : dst1;
  ushort_t* partial = tower ? partial2 : partial1;
  int color = bid & (NCOLOR - 1);
  int sub = bid >> CSHIFT;
  int base = color * rng;
  int hi = n - base; if (hi > rng) hi = rng;
  for (int i = threadIdx.x; i < rng; i += 256) hist[i] = 0;
  __syncthreads();
  const int stride = KB * 256;
  int e = sub * 256 + threadIdx.x;
  for (; e + 7 * stride < E; e += 8 * stride) {
    int d[8];
#pragma unroll
    for (int k = 0; k < 8; ++k) d[k] = dst[e + k * stride] - base;
#pragma unroll
    for (int k = 0; k < 8; ++k)
      if ((unsigned)d[k] < (unsigned)hi) atomicAdd(&hist[d[k]], 1);
  }
  for (; e < E; e += stride) {
    int d = dst[e] - base;
    if ((unsigned)d < (unsigned)hi) atomicAdd(&hist[d], 1);
  }
  __syncthreads();
  ushort_t* outp = partial + (size_t)bid * rng;
  for (int i = threadIdx.x; i < rng; i += 256) outp[i] = (ushort_t)hist[i];
}

// ---------- pass2 (merged): reduce partials -> cnt (padded layout) + dinv ----
__global__ void k_reduce_part(ushort_t* __restrict__ partial1,
                              ushort_t* __restrict__ partial2, int* __restrict__ cnt,
                              float* __restrict__ dinv, int n, int npad, int rng) {
  int gi = blockIdx.x * 256 + threadIdx.x;  // over 2*npad
  int tower = gi >= npad;
  int li = gi - (tower ? npad : 0);
  if (li >= n) { cnt[gi] = 0; return; }  // pad region
  ushort_t* partial = tower ? partial2 : partial1;
  int c = li / rng, lli = li - c * rng;
  int acc = 0;
  for (int s = 0; s < KB; ++s) {
    size_t idx = (size_t)(s * NCOLOR + c) * rng + lli;
    int t = partial[idx];
    partial[idx] = (ushort_t)acc;
    acc += t;
  }
  cnt[gi] = acc;
  dinv[tower * n + li] = 1.0f / sqrtf((float)(acc + 1));  // self-loop => deg >= 1
}

// ---------- segmented 3-phase exclusive scan over 2 towers ----------
__global__ void k_scan1(const int* __restrict__ cnt, int* __restrict__ off,
                        int* __restrict__ bsums, int n, int npad) {
  __shared__ int s[256];
  int tid = threadIdx.x;
  int gid = blockIdx.x * 256 + tid;  // grid = 2*npad/256 exactly
  int v = cnt[gid];
  s[tid] = v; __syncthreads();
  for (int o = 1; o < 256; o <<= 1) {
    int t = (tid >= o) ? s[tid - o] : 0;
    __syncthreads();
    s[tid] += t;
    __syncthreads();
  }
  int tower = gid >= npad;
  int li = gid - (tower ? npad : 0);
  if (li < n) off[tower * (n + 1) + li] = s[tid] - v;
  if (tid == 255) bsums[blockIdx.x] = s[255];
}

__global__ void k_scan2(int* __restrict__ bsums, int nb, int segstart) {
  __shared__ int s[1024];
  __shared__ int seg0;
  int tid = threadIdx.x;
  int v = (tid < nb) ? bsums[tid] : 0;
  s[tid] = v; __syncthreads();
  for (int o = 1; o < 1024; o <<= 1) {
    int t = (tid >= o) ? s[tid - o] : 0;
    __syncthreads();
    s[tid] += t;
    __syncthreads();
  }
  int excl = s[tid] - v;
  if (tid == segstart) seg0 = excl;  // sum of tower-1 blocks
  __syncthreads();
  if (tid < nb) bsums[tid] = (tid >= segstart) ? excl - seg0 : excl;
}

__global__ void k_off_final(int* __restrict__ off, const int* __restrict__ bsums,
                            int n, int npad, int E) {
  int gid = blockIdx.x * 256 + threadIdx.x;
  int tower = gid >= npad;
  int li = gid - (tower ? npad : 0);
  if (li < n) off[tower * (n + 1) + li] += bsums[blockIdx.x];
  if (li == 0) off[tower * (n + 1) + n] = E;
}

// ---------- pass4 (merged): colored CSR fill; tower-2 rows stored +n, window +E --
__global__ __launch_bounds__(256) void k_fill_col(const int* __restrict__ src1,
                                                  const int* __restrict__ dst1,
                                                  const int* __restrict__ src2,
                                                  const int* __restrict__ dst2,
                                                  const int* __restrict__ off,
                                                  const ushort_t* __restrict__ partial1,
                                                  const ushort_t* __restrict__ partial2,
                                                  int* __restrict__ csr, int E, int n,
                                                  int rng) {
  extern __shared__ int cur[];
  const int tbase = NCOLOR * KB;
  int tower = blockIdx.x >= tbase;
  int bid = blockIdx.x - (tower ? tbase : 0);
  const int* src = tower ? src2 : src1;
  const int* dst = tower ? dst2 : dst1;
  const ushort_t* partial = tower ? partial2 : partial1;
  const int* offt = off + tower * (n + 1);
  int cbase = tower ? E : 0;
  int nodeoff = tower ? n : 0;
  int color = bid & (NCOLOR - 1);
  int sub = bid >> CSHIFT;
  int base = color * rng;
  int hi = n - base; if (hi > rng) hi = rng;
  const ushort_t* pp = partial + (size_t)bid * rng;
  for (int i = threadIdx.x; i < hi; i += 256)
    cur[i] = offt[base + i] + (int)pp[i] + cbase;
  __syncthreads();
  const int stride = KB * 256;
  int e = sub * 256 + threadIdx.x;
  for (; e + 7 * stride < E; e += 8 * stride) {
    int d[8], s[8];
#pragma unroll
    for (int k = 0; k < 8; ++k) d[k] = dst[e + k * stride] - base;
#pragma unroll
    for (int k = 0; k < 8; ++k) s[k] = src[e + k * stride];  // unconditional: pipeline
#pragma unroll
    for (int k = 0; k < 8; ++k) {
      if ((unsigned)d[k] < (unsigned)hi) {
        int p = atomicAdd(&cur[d[k]], 1);
        csr[p] = s[k] + nodeoff;
      }
    }
  }
  for (; e < E; e += stride) {
    int d = dst[e] - base;
    if ((unsigned)d < (unsigned)hi) {
      int p = atomicAdd(&cur[d], 1);
      csr[p] = src[e] + nodeoff;
    }
  }
}

// ---------- MFMA GEMM (merged): out[r] = dinv[r]*(in[r]@W), r over 2n rows ----
template <int K, int INF32>
__global__ __launch_bounds__(256, 2) void k_gemm_mfma(const float* __restrict__ xf1,
                                                      const float* __restrict__ xf2,
                                                      const bf16* __restrict__ xb,
                                                      const float* __restrict__ Wg,
                                                      const float* __restrict__ dinv,
                                                      bf16* __restrict__ out, int n2,
                                                      int nper) {
  constexpr int KS = K / 32;
  int lane = threadIdx.x & 63;
  int quad = lane >> 4;
  int col = lane & 15;

  bf8_t bfrag[4][KS];
#pragma unroll
  for (int c = 0; c < 4; ++c)
#pragma unroll
    for (int s = 0; s < KS; ++s)
#pragma unroll
      for (int j = 0; j < 8; ++j)
        bfrag[c][s][j] = f2bbits(Wg[(s * 32 + quad * 8 + j) * 64 + c * 16 + col]);

  int wid = (blockIdx.x * blockDim.x + threadIdx.x) >> 6;
  int nw = (gridDim.x * blockDim.x) >> 6;
  int tiles = (n2 + 15) >> 4;
  for (int t = wid; t < tiles; t += nw) {
    int base = t << 4;
    int arow = base + col;
    if (arow >= n2) arow = n2 - 1;

    bf8_t afrag[KS];
    if (INF32) {
      int tower = arow >= nper;  // nper % 16 == 0 -> tiles never straddle
      const float* xr = (tower ? xf2 : xf1) +
                        (size_t)(arow - (tower ? nper : 0)) * K;
#pragma unroll
      for (int s = 0; s < KS; ++s) {
        float4 u0 = *(const float4*)(xr + s * 32 + quad * 8);
        float4 u1 = *(const float4*)(xr + s * 32 + quad * 8 + 4);
        afrag[s][0] = f2bbits(u0.x);
        afrag[s][1] = f2bbits(u0.y);
        afrag[s][2] = f2bbits(u0.z);
        afrag[s][3] = f2bbits(u0.w);
        afrag[s][4] = f2bbits(u1.x);
        afrag[s][5] = f2bbits(u1.y);
        afrag[s][6] = f2bbits(u1.z);
        afrag[s][7] = f2bbits(u1.w);
      }
    } else {
      const bf16* xr = xb + (size_t)arow * K;
#pragma unroll
      for (int s = 0; s < KS; ++s)
        afrag[s] = *(const bf8_t*)(xr + s * 32 + quad * 8);
    }

    f4_t acc[4];
#pragma unroll
    for (int c = 0; c < 4; ++c) acc[c] = (f4_t){0.f, 0.f, 0.f, 0.f};
#pragma unroll
    for (int s = 0; s < KS; ++s)
#pragma unroll
      for (int c = 0; c < 4; ++c)
        acc[c] = __builtin_amdgcn_mfma_f32_16x16x32_bf16(afrag[s], bfrag[c][s],
                                                         acc[c], 0, 0, 0);
#pragma unroll
    for (int r = 0; r < 4; ++r) {
      int row = base + quad * 4 + r;
      if (row < n2) {
        float sc = dinv[row];
#pragma unroll
        for (int c = 0; c < 4; ++c)
          out[(size_t)row * 64 + c * 16 + col] = f2b(acc[c][r] * sc);
      }
    }
  }
}

// ---------- aggregate (R10 body, merged towers) ----------
// MODE 0: out = bf16 relu(dinv*acc + b)        (layer 1)
// MODE 1: out = bf16 dinv*relu(dinv*acc + b)   (layer 2, emits x')
template <int MODE>
__global__ __launch_bounds__(256) void k_agg(const bf16* __restrict__ hp,
                                             const int* __restrict__ off,
                                             const int* __restrict__ csr,
                                             const float* __restrict__ dinv,
                                             const float* __restrict__ bias,
                                             bf16* __restrict__ outv, int n2,
                                             int nper, int E) {
  int lane = threadIdx.x & 63;
  int wid = (blockIdx.x * blockDim.x + threadIdx.x) >> 6;
  int nw = (gridDim.x * blockDim.x) >> 6;
  float b = bias[lane];
  for (int node = wid; node < n2; node += nw) {
    int un = wave_uniform(node);
    int tower = un >= nper;
    int ln = un - (tower ? nper : 0);
    const int* o = off + tower * (nper + 1);
    int cb = tower ? E : 0;
    int beg = o[ln] + cb, end = o[ln + 1] + cb;
    float acc = b2f(hp[(size_t)un * 64 + lane]);  // self-loop
    int e = beg;
    int efull = beg + ((end - beg) & ~7);
    for (; e < efull; e += 8) {
      int s0 = csr[e + 0], s1 = csr[e + 1], s2 = csr[e + 2], s3 = csr[e + 3];
      int s4 = csr[e + 4], s5 = csr[e + 5], s6 = csr[e + 6], s7 = csr[e + 7];
      float a0 = b2f(hp[(size_t)s0 * 64 + lane]);
      float a1 = b2f(hp[(size_t)s1 * 64 + lane]);
      float a2 = b2f(hp[(size_t)s2 * 64 + lane]);
      float a3 = b2f(hp[(size_t)s3 * 64 + lane]);
      float a4 = b2f(hp[(size_t)s4 * 64 + lane]);
      float a5 = b2f(hp[(size_t)s5 * 64 + lane]);
      float a6 = b2f(hp[(size_t)s6 * 64 + lane]);
      float a7 = b2f(hp[(size_t)s7 * 64 + lane]);
      acc += ((a0 + a1) + (a2 + a3)) + ((a4 + a5) + (a6 + a7));
    }
    int rem = end - e;  // 0..7, wave-uniform -> s_cbranch
    if (rem & 4) {
      int s0 = csr[e + 0], s1 = csr[e + 1], s2 = csr[e + 2], s3 = csr[e + 3];
      float a0 = b2f(hp[(size_t)s0 * 64 + lane]);
      float a1 = b2f(hp[(size_t)s1 * 64 + lane]);
      float a2 = b2f(hp[(size_t)s2 * 64 + lane]);
      float a3 = b2f(hp[(size_t)s3 * 64 + lane]);
      acc += (a0 + a1) + (a2 + a3);
      e += 4;
    }
    if (rem & 2) {
      int s0 = csr[e + 0], s1 = csr[e + 1];
      float a0 = b2f(hp[(size_t)s0 * 64 + lane]);
      float a1 = b2f(hp[(size_t)s1 * 64 + lane]);
      acc += a0 + a1;
      e += 2;
    }
    if (rem & 1) {
      acc += b2f(hp[(size_t)csr[e] * 64 + lane]);
    }
    float di = dinv[un];
    float v = fmaf(acc, di, b);
    v = fmaxf(v, 0.f);
    if (MODE == 1) v *= di;  // emit x' = dinv * relu(r)
    outv[(size_t)un * 64 + lane] = f2b(v);
  }
}

// ---------- folded layer-3 agg + mean-pool accumulate (atomicAdd) ----------
// t_v = dinv_v * (x'_v + sum x'_u); pooled[batch[v]] += t_v; cnt[batch[v]] += 1.
__global__ __launch_bounds__(256) void k_agg_pool(const bf16* __restrict__ hp,
                                                  const int* __restrict__ off,
                                                  const int* __restrict__ csr,
                                                  const float* __restrict__ dinv,
                                                  const int* __restrict__ batch1,
                                                  const int* __restrict__ batch2,
                                                  float* __restrict__ pooled1,
                                                  float* __restrict__ cnt1,
                                                  float* __restrict__ pooled2,
                                                  float* __restrict__ cnt2, int n2,
                                                  int nper, int E) {
  int lane = threadIdx.x & 63;
  int wid = (blockIdx.x * blockDim.x + threadIdx.x) >> 6;
  int nw = (gridDim.x * blockDim.x) >> 6;
  for (int node = wid; node < n2; node += nw) {
    int un = wave_uniform(node);
    int tower = un >= nper;
    int ln = un - (tower ? nper : 0);
    const int* o = off + tower * (nper + 1);
    int cb = tower ? E : 0;
    int beg = o[ln] + cb, end = o[ln + 1] + cb;
    float acc = b2f(hp[(size_t)un * 64 + lane]);  // self-loop
    int e = beg;
    int efull = beg + ((end - beg) & ~7);
    for (; e < efull; e += 8) {
      int s0 = csr[e + 0], s1 = csr[e + 1], s2 = csr[e + 2], s3 = csr[e + 3];
      int s4 = csr[e + 4], s5 = csr[e + 5], s6 = csr[e + 6], s7 = csr[e + 7];
      float a0 = b2f(hp[(size_t)s0 * 64 + lane]);
      float a1 = b2f(hp[(size_t)s1 * 64 + lane]);
      float a2 = b2f(hp[(size_t)s2 * 64 + lane]);
      float a3 = b2f(hp[(size_t)s3 * 64 + lane]);
      float a4 = b2f(hp[(size_t)s4 * 64 + lane]);
      float a5 = b2f(hp[(size_t)s5 * 64 + lane]);
      float a6 = b2f(hp[(size_t)s6 * 64 + lane]);
      float a7 = b2f(hp[(size_t)s7 * 64 + lane]);
      acc += ((a0 + a1) + (a2 + a3)) + ((a4 + a5) + (a6 + a7));
    }
    int rem = end - e;
    if (rem & 4) {
      int s0 = csr[e + 0], s1 = csr[e + 1], s2 = csr[e + 2], s3 = csr[e + 3];
      float a0 = b2f(hp[(size_t)s0 * 64 + lane]);
      float a1 = b2f(hp[(size_t)s1 * 64 + lane]);
      float a2 = b2f(hp[(size_t)s2 * 64 + lane]);
      float a3 = b2f(hp[(size_t)s3 * 64 + lane]);
      acc += (a0 + a1) + (a2 + a3);
      e += 4;
    }
    if (rem & 2) {
      int s0 = csr[e + 0], s1 = csr[e + 1];
      float a0 = b2f(hp[(size_t)s0 * 64 + lane]);
      float a1 = b2f(hp[(size_t)s1 * 64 + lane]);
      acc += a0 + a1;
      e += 2;
    }
    if (rem & 1) {
      acc += b2f(hp[(size_t)csr[e] * 64 + lane]);
    }
    float t = acc * dinv[un];
    const int* batch = tower ? batch2 : batch1;
    float* pooled = tower ? pooled2 : pooled1;
    float* cntp = tower ? cnt2 : cnt1;
    int g = batch[ln];  // uniform
    atomicAdd(&pooled[g * 64 + lane], t);
    if (lane == 0) atomicAdd(&cntp[g], 1.0f);
  }
}

// ---------- head: (mean t)@W3 + b3, then @Wlin + blin, L2 distance ----------
__global__ void k_final(const float* __restrict__ pooled1, const float* __restrict__ cnt1,
                        const float* __restrict__ pooled2, const float* __restrict__ cnt2,
                        const float* __restrict__ W3, const float* __restrict__ b3,
                        const float* __restrict__ Wlin, const float* __restrict__ blin,
                        float* __restrict__ outp) {
  int g = blockIdx.x;
  int lane = threadIdx.x;  // 64 threads
  float c1 = fmaxf(cnt1[g], 1.f), c2 = fmaxf(cnt2[g], 1.f);
  float p1 = pooled1[g * 64 + lane] / c1;
  float p2 = pooled2[g * 64 + lane] / c2;
  // stage 1: q = p @ W3 + b3
  float q1 = b3[lane], q2 = b3[lane];
  for (int j = 0; j < 64; ++j) {
    float w = W3[j * 64 + lane];
    q1 = fmaf(__shfl(p1, j), w, q1);
    q2 = fmaf(__shfl(p2, j), w, q2);
  }
  // stage 2: e = q @ Wlin + blin
  float e1 = blin[lane], e2 = blin[lane];
  for (int j = 0; j < 64; ++j) {
    float w = Wlin[j * 64 + lane];
    e1 = fmaf(__shfl(q1, j), w, e1);
    e2 = fmaf(__shfl(q2, j), w, e2);
  }
  float d = e1 - e2 + PD_EPS;
  float sq = d * d;
  for (int o = 32; o > 0; o >>= 1) sq += __shfl_down(sq, o);
  if (lane == 0) outp[g] = sqrtf(sq);
}

extern "C" void kernel_launch(void* const* d_in, const int* in_sizes, int n_in,
                              void* d_out, int out_size, void* d_ws, size_t ws_size,
                              hipStream_t stream) {
  const float* x1 = (const float*)d_in[0];
  const int* ei1 = (const int*)d_in[1];
  const int* batch1 = (const int*)d_in[2];
  const float* x2 = (const float*)d_in[3];
  const int* ei2 = (const int*)d_in[4];
  const int* batch2 = (const int*)d_in[5];
  const float* W1 = (const float*)d_in[6];
  const float* b1 = (const float*)d_in[7];
  const float* W2 = (const float*)d_in[8];
  const float* b2 = (const float*)d_in[9];
  const float* W3 = (const float*)d_in[10];
  const float* b3 = (const float*)d_in[11];
  const float* Wlin = (const float*)d_in[12];
  const float* blin = (const float*)d_in[13];

  const int N = in_sizes[2];      // 100000
  const int E = in_sizes[1] / 2;  // 1600000
  const int rng = (N + NCOLOR - 1) / NCOLOR;  // nodes per color (6250)
  const int nbN = (N + 255) / 256;            // 391
  const int Npad = nbN * 256;                 // 100096 (block-aligned segment)
  const int nb2 = 2 * nbN;                    // 782 scan blocks

  const int* src1 = ei1; const int* dst1 = ei1 + E;
  const int* src2 = ei2; const int* dst2 = ei2 + E;

  // workspace carve (~105 MB of 268 MB)
  char* p = (char*)d_ws;
  auto alloc = [&](size_t bytes) {
    char* r = p;
    p += (bytes + 255) & ~(size_t)255;
    return r;
  };
  int* off = (int*)alloc((size_t)2 * (N + 1) * 4);
  int* cntn = (int*)alloc((size_t)2 * Npad * 4);
  int* bsums = (int*)alloc(1024 * 4);
  float* dinv = (float*)alloc((size_t)2 * N * 4);
  int* csr = (int*)alloc((size_t)2 * E * 4);
  ushort_t* partial1 = (ushort_t*)alloc((size_t)NCOLOR * KB * rng * 2);
  ushort_t* partial2 = (ushort_t*)alloc((size_t)NCOLOR * KB * rng * 2);
  bf16* hpA = (bf16*)alloc((size_t)2 * N * 64 * 2);
  bf16* hpB = (bf16*)alloc((size_t)2 * N * 64 * 2);
  // pooled1,cnt1,pooled2,cnt2 contiguous -> ONE memset covers all four
  float* pooled1 = (float*)alloc((size_t)NGRAPHS * 64 * 4);
  float* cnt1 = (float*)alloc((size_t)NGRAPHS * 4);
  float* pooled2 = (float*)alloc((size_t)NGRAPHS * 64 * 4);
  float* cnt2 = (float*)alloc((size_t)NGRAPHS * 4);
  size_t poolspan = (size_t)((char*)(cnt2 + NGRAPHS) - (char*)pooled1);

  const size_t ldsB = (size_t)rng * 4;  // 25 KB dynamic LDS -> 6 blocks/CU
  const int N2 = 2 * N;

  hipMemsetAsync(pooled1, 0, poolspan, stream);

  // CSR build, both towers in one pass each
  k_count_part<<<2 * NCOLOR * KB, 256, ldsB, stream>>>(dst1, dst2, partial1,
                                                       partial2, E, N, rng);
  k_reduce_part<<<nb2, 256, 0, stream>>>(partial1, partial2, cntn, dinv, N, Npad,
                                         rng);
  k_scan1<<<nb2, 256, 0, stream>>>(cntn, off, bsums, N, Npad);
  k_scan2<<<1, 1024, 0, stream>>>(bsums, nb2, nbN);
  k_off_final<<<nb2, 256, 0, stream>>>(off, bsums, N, Npad, E);
  k_fill_col<<<2 * NCOLOR * KB, 256, ldsB, stream>>>(src1, dst1, src2, dst2, off,
                                                     partial1, partial2, csr, E, N,
                                                     rng);

  // layer 1 (both towers)
  k_gemm_mfma<128, 1><<<1024, 256, 0, stream>>>(x1, x2, (const bf16*)nullptr, W1,
                                                dinv, hpA, N2, N);
  k_agg<0><<<4096, 256, 0, stream>>>(hpA, off, csr, dinv, b1, hpB, N2, N, E);
  // layer 2 (emits x' = dinv*relu(r2))
  k_gemm_mfma<64, 0><<<1024, 256, 0, stream>>>((const float*)nullptr,
                                               (const float*)nullptr, hpB, W2, dinv,
                                               hpA, N2, N);
  k_agg<1><<<4096, 256, 0, stream>>>(hpA, off, csr, dinv, b2, hpB, N2, N, E);
  // layer 3 folded + mean-pool accumulate
  k_agg_pool<<<4096, 256, 0, stream>>>(hpB, off, csr, dinv, batch1, batch2, pooled1,
                                       cnt1, pooled2, cnt2, N2, N, E);

  k_final<<<NGRAPHS, 64, 0, stream>>>(pooled1, cnt1, pooled2, cnt2, W3, b3, Wlin,
                                      blin, (float*)d_out);
}

// Round 7
// 532.851 us; speedup vs baseline: 1.7620x; 1.7620x over previous
//
#include <hip/hip_runtime.h>
#include <hip/hip_bf16.h>
#include <math.h>

#define NGRAPHS 256
#define PD_EPS 1e-6f
#define POOL_CHUNK 64
#define NCOLOR 16  // csr-build colors; color = bid & 15 (write-merged csr window,
                   // R4/R6). 16 colors -> 25KB LDS hist/cursor -> 6 blocks/CU.
#define CSHIFT 4
#define KB 96      // blocks per color per tower; 1536/tower = 6/CU LDS cap.
// R7: color = bid/KB scatters csr writes across XCDs. Keep bid&15.
// R9: fill/count serial-latency-bound -> 8-deep load pipeline (WIN).
// R10: exact-load agg (8-wide + 4/2/1 uniform tail) = proven-best agg; R11/R12
// alternatives failed: agg is latency x concurrency bound at the fabric wall.
// R13: folded layer-3 GEMM into k_final (WIN, -105us).
// R14: tower-merge all kernels (WIN for build/gemm/agg) BUT agg+pool fusion
// REGRESSED 517us: per-node 256B atomicAdd onto 256 sorted graph rows ->
// L2 atomic serialization (VALU 4%, HBM 6%). Guideline-12 violation.
// R15: keep tower merge; layer 3 back to split agg<2> (f32 bufF) + chunked
// k_pool (64-node local accumulate, ~3k atomics total), pool tower-merged.

typedef __hip_bfloat16 bf16;
typedef unsigned short ushort_t;
typedef short bf8_t __attribute__((ext_vector_type(8)));   // 8 bf16 = 4 VGPRs
typedef float f4_t __attribute__((ext_vector_type(4)));    // MFMA accumulator

static __device__ __forceinline__ int wave_uniform(int v) {
  return __builtin_amdgcn_readfirstlane(v);
}
static __device__ __forceinline__ float b2f(bf16 h) { return __bfloat162float(h); }
static __device__ __forceinline__ bf16 f2b(float f) { return __float2bfloat16(f); }
static __device__ __forceinline__ short f2bbits(float f) {
  bf16 h = __float2bfloat16(f);
  return *reinterpret_cast<short*>(&h);
}

// ---------- pass1 (merged towers): per-(tower,color,block) degree hist ----------
__global__ __launch_bounds__(256) void k_count_part(const int* __restrict__ dst1,
                                                    const int* __restrict__ dst2,
                                                    ushort_t* __restrict__ partial1,
                                                    ushort_t* __restrict__ partial2,
                                                    int E, int n, int rng) {
  extern __shared__ int hist[];
  const int tbase = NCOLOR * KB;
  int tower = blockIdx.x >= tbase;
  int bid = blockIdx.x - (tower ? tbase : 0);
  const int* dst = tower ? dst2 : dst1;
  ushort_t* partial = tower ? partial2 : partial1;
  int color = bid & (NCOLOR - 1);
  int sub = bid >> CSHIFT;
  int base = color * rng;
  int hi = n - base; if (hi > rng) hi = rng;
  for (int i = threadIdx.x; i < rng; i += 256) hist[i] = 0;
  __syncthreads();
  const int stride = KB * 256;
  int e = sub * 256 + threadIdx.x;
  for (; e + 7 * stride < E; e += 8 * stride) {
    int d[8];
#pragma unroll
    for (int k = 0; k < 8; ++k) d[k] = dst[e + k * stride] - base;
#pragma unroll
    for (int k = 0; k < 8; ++k)
      if ((unsigned)d[k] < (unsigned)hi) atomicAdd(&hist[d[k]], 1);
  }
  for (; e < E; e += stride) {
    int d = dst[e] - base;
    if ((unsigned)d < (unsigned)hi) atomicAdd(&hist[d], 1);
  }
  __syncthreads();
  ushort_t* outp = partial + (size_t)bid * rng;
  for (int i = threadIdx.x; i < rng; i += 256) outp[i] = (ushort_t)hist[i];
}

// ---------- pass2 (merged): reduce partials -> cnt (padded layout) + dinv ----
__global__ void k_reduce_part(ushort_t* __restrict__ partial1,
                              ushort_t* __restrict__ partial2, int* __restrict__ cnt,
                              float* __restrict__ dinv, int n, int npad, int rng) {
  int gi = blockIdx.x * 256 + threadIdx.x;  // over 2*npad
  int tower = gi >= npad;
  int li = gi - (tower ? npad : 0);
  if (li >= n) { cnt[gi] = 0; return; }  // pad region
  ushort_t* partial = tower ? partial2 : partial1;
  int c = li / rng, lli = li - c * rng;
  int acc = 0;
  for (int s = 0; s < KB; ++s) {
    size_t idx = (size_t)(s * NCOLOR + c) * rng + lli;
    int t = partial[idx];
    partial[idx] = (ushort_t)acc;
    acc += t;
  }
  cnt[gi] = acc;
  dinv[tower * n + li] = 1.0f / sqrtf((float)(acc + 1));  // self-loop => deg >= 1
}

// ---------- segmented 3-phase exclusive scan over 2 towers ----------
__global__ void k_scan1(const int* __restrict__ cnt, int* __restrict__ off,
                        int* __restrict__ bsums, int n, int npad) {
  __shared__ int s[256];
  int tid = threadIdx.x;
  int gid = blockIdx.x * 256 + tid;  // grid = 2*npad/256 exactly
  int v = cnt[gid];
  s[tid] = v; __syncthreads();
  for (int o = 1; o < 256; o <<= 1) {
    int t = (tid >= o) ? s[tid - o] : 0;
    __syncthreads();
    s[tid] += t;
    __syncthreads();
  }
  int tower = gid >= npad;
  int li = gid - (tower ? npad : 0);
  if (li < n) off[tower * (n + 1) + li] = s[tid] - v;
  if (tid == 255) bsums[blockIdx.x] = s[255];
}

__global__ void k_scan2(int* __restrict__ bsums, int nb, int segstart) {
  __shared__ int s[1024];
  __shared__ int seg0;
  int tid = threadIdx.x;
  int v = (tid < nb) ? bsums[tid] : 0;
  s[tid] = v; __syncthreads();
  for (int o = 1; o < 1024; o <<= 1) {
    int t = (tid >= o) ? s[tid - o] : 0;
    __syncthreads();
    s[tid] += t;
    __syncthreads();
  }
  int excl = s[tid] - v;
  if (tid == segstart) seg0 = excl;  // sum of tower-1 blocks
  __syncthreads();
  if (tid < nb) bsums[tid] = (tid >= segstart) ? excl - seg0 : excl;
}

__global__ void k_off_final(int* __restrict__ off, const int* __restrict__ bsums,
                            int n, int npad, int E) {
  int gid = blockIdx.x * 256 + threadIdx.x;
  int tower = gid >= npad;
  int li = gid - (tower ? npad : 0);
  if (li < n) off[tower * (n + 1) + li] += bsums[blockIdx.x];
  if (li == 0) off[tower * (n + 1) + n] = E;
}

// ---------- pass4 (merged): colored CSR fill; tower-2 rows stored +n, window +E --
__global__ __launch_bounds__(256) void k_fill_col(const int* __restrict__ src1,
                                                  const int* __restrict__ dst1,
                                                  const int* __restrict__ src2,
                                                  const int* __restrict__ dst2,
                                                  const int* __restrict__ off,
                                                  const ushort_t* __restrict__ partial1,
                                                  const ushort_t* __restrict__ partial2,
                                                  int* __restrict__ csr, int E, int n,
                                                  int rng) {
  extern __shared__ int cur[];
  const int tbase = NCOLOR * KB;
  int tower = blockIdx.x >= tbase;
  int bid = blockIdx.x - (tower ? tbase : 0);
  const int* src = tower ? src2 : src1;
  const int* dst = tower ? dst2 : dst1;
  const ushort_t* partial = tower ? partial2 : partial1;
  const int* offt = off + tower * (n + 1);
  int cbase = tower ? E : 0;
  int nodeoff = tower ? n : 0;
  int color = bid & (NCOLOR - 1);
  int sub = bid >> CSHIFT;
  int base = color * rng;
  int hi = n - base; if (hi > rng) hi = rng;
  const ushort_t* pp = partial + (size_t)bid * rng;
  for (int i = threadIdx.x; i < hi; i += 256)
    cur[i] = offt[base + i] + (int)pp[i] + cbase;
  __syncthreads();
  const int stride = KB * 256;
  int e = sub * 256 + threadIdx.x;
  for (; e + 7 * stride < E; e += 8 * stride) {
    int d[8], s[8];
#pragma unroll
    for (int k = 0; k < 8; ++k) d[k] = dst[e + k * stride] - base;
#pragma unroll
    for (int k = 0; k < 8; ++k) s[k] = src[e + k * stride];  // unconditional: pipeline
#pragma unroll
    for (int k = 0; k < 8; ++k) {
      if ((unsigned)d[k] < (unsigned)hi) {
        int p = atomicAdd(&cur[d[k]], 1);
        csr[p] = s[k] + nodeoff;
      }
    }
  }
  for (; e < E; e += stride) {
    int d = dst[e] - base;
    if ((unsigned)d < (unsigned)hi) {
      int p = atomicAdd(&cur[d], 1);
      csr[p] = src[e] + nodeoff;
    }
  }
}

// ---------- MFMA GEMM (merged): out[r] = dinv[r]*(in[r]@W), r over 2n rows ----
template <int K, int INF32>
__global__ __launch_bounds__(256, 2) void k_gemm_mfma(const float* __restrict__ xf1,
                                                      const float* __restrict__ xf2,
                                                      const bf16* __restrict__ xb,
                                                      const float* __restrict__ Wg,
                                                      const float* __restrict__ dinv,
                                                      bf16* __restrict__ out, int n2,
                                                      int nper) {
  constexpr int KS = K / 32;
  int lane = threadIdx.x & 63;
  int quad = lane >> 4;
  int col = lane & 15;

  bf8_t bfrag[4][KS];
#pragma unroll
  for (int c = 0; c < 4; ++c)
#pragma unroll
    for (int s = 0; s < KS; ++s)
#pragma unroll
      for (int j = 0; j < 8; ++j)
        bfrag[c][s][j] = f2bbits(Wg[(s * 32 + quad * 8 + j) * 64 + c * 16 + col]);

  int wid = (blockIdx.x * blockDim.x + threadIdx.x) >> 6;
  int nw = (gridDim.x * blockDim.x) >> 6;
  int tiles = (n2 + 15) >> 4;
  for (int t = wid; t < tiles; t += nw) {
    int base = t << 4;
    int arow = base + col;
    if (arow >= n2) arow = n2 - 1;

    bf8_t afrag[KS];
    if (INF32) {
      int tower = arow >= nper;  // nper % 16 == 0 -> tiles never straddle
      const float* xr = (tower ? xf2 : xf1) +
                        (size_t)(arow - (tower ? nper : 0)) * K;
#pragma unroll
      for (int s = 0; s < KS; ++s) {
        float4 u0 = *(const float4*)(xr + s * 32 + quad * 8);
        float4 u1 = *(const float4*)(xr + s * 32 + quad * 8 + 4);
        afrag[s][0] = f2bbits(u0.x);
        afrag[s][1] = f2bbits(u0.y);
        afrag[s][2] = f2bbits(u0.z);
        afrag[s][3] = f2bbits(u0.w);
        afrag[s][4] = f2bbits(u1.x);
        afrag[s][5] = f2bbits(u1.y);
        afrag[s][6] = f2bbits(u1.z);
        afrag[s][7] = f2bbits(u1.w);
      }
    } else {
      const bf16* xr = xb + (size_t)arow * K;
#pragma unroll
      for (int s = 0; s < KS; ++s)
        afrag[s] = *(const bf8_t*)(xr + s * 32 + quad * 8);
    }

    f4_t acc[4];
#pragma unroll
    for (int c = 0; c < 4; ++c) acc[c] = (f4_t){0.f, 0.f, 0.f, 0.f};
#pragma unroll
    for (int s = 0; s < KS; ++s)
#pragma unroll
      for (int c = 0; c < 4; ++c)
        acc[c] = __builtin_amdgcn_mfma_f32_16x16x32_bf16(afrag[s], bfrag[c][s],
                                                         acc[c], 0, 0, 0);
#pragma unroll
    for (int r = 0; r < 4; ++r) {
      int row = base + quad * 4 + r;
      if (row < n2) {
        float sc = dinv[row];
#pragma unroll
        for (int c = 0; c < 4; ++c)
          out[(size_t)row * 64 + c * 16 + col] = f2b(acc[c][r] * sc);
      }
    }
  }
}

// ---------- aggregate (R10 body, merged towers) ----------
// MODE 0: out = bf16 relu(dinv*acc + b)        (layer 1)
// MODE 1: out = bf16 dinv*relu(dinv*acc + b)   (layer 2, emits x')
// MODE 2: out = f32  dinv*acc                  (folded layer 3 -> bufF)
template <int MODE>
__global__ __launch_bounds__(256) void k_agg(const bf16* __restrict__ hp,
                                             const int* __restrict__ off,
                                             const int* __restrict__ csr,
                                             const float* __restrict__ dinv,
                                             const float* __restrict__ bias,
                                             void* __restrict__ outv, int n2,
                                             int nper, int E) {
  int lane = threadIdx.x & 63;
  int wid = (blockIdx.x * blockDim.x + threadIdx.x) >> 6;
  int nw = (gridDim.x * blockDim.x) >> 6;
  float b = (MODE == 2) ? 0.f : bias[lane];
  for (int node = wid; node < n2; node += nw) {
    int un = wave_uniform(node);
    int tower = un >= nper;
    int ln = un - (tower ? nper : 0);
    const int* o = off + tower * (nper + 1);
    int cb = tower ? E : 0;
    int beg = o[ln] + cb, end = o[ln + 1] + cb;
    float acc = b2f(hp[(size_t)un * 64 + lane]);  // self-loop
    int e = beg;
    int efull = beg + ((end - beg) & ~7);
    for (; e < efull; e += 8) {
      int s0 = csr[e + 0], s1 = csr[e + 1], s2 = csr[e + 2], s3 = csr[e + 3];
      int s4 = csr[e + 4], s5 = csr[e + 5], s6 = csr[e + 6], s7 = csr[e + 7];
      float a0 = b2f(hp[(size_t)s0 * 64 + lane]);
      float a1 = b2f(hp[(size_t)s1 * 64 + lane]);
      float a2 = b2f(hp[(size_t)s2 * 64 + lane]);
      float a3 = b2f(hp[(size_t)s3 * 64 + lane]);
      float a4 = b2f(hp[(size_t)s4 * 64 + lane]);
      float a5 = b2f(hp[(size_t)s5 * 64 + lane]);
      float a6 = b2f(hp[(size_t)s6 * 64 + lane]);
      float a7 = b2f(hp[(size_t)s7 * 64 + lane]);
      acc += ((a0 + a1) + (a2 + a3)) + ((a4 + a5) + (a6 + a7));
    }
    int rem = end - e;  // 0..7, wave-uniform -> s_cbranch
    if (rem & 4) {
      int s0 = csr[e + 0], s1 = csr[e + 1], s2 = csr[e + 2], s3 = csr[e + 3];
      float a0 = b2f(hp[(size_t)s0 * 64 + lane]);
      float a1 = b2f(hp[(size_t)s1 * 64 + lane]);
      float a2 = b2f(hp[(size_t)s2 * 64 + lane]);
      float a3 = b2f(hp[(size_t)s3 * 64 + lane]);
      acc += (a0 + a1) + (a2 + a3);
      e += 4;
    }
    if (rem & 2) {
      int s0 = csr[e + 0], s1 = csr[e + 1];
      float a0 = b2f(hp[(size_t)s0 * 64 + lane]);
      float a1 = b2f(hp[(size_t)s1 * 64 + lane]);
      acc += a0 + a1;
      e += 2;
    }
    if (rem & 1) {
      acc += b2f(hp[(size_t)csr[e] * 64 + lane]);
    }
    float di = dinv[un];
    if (MODE == 2) {
      ((float*)outv)[(size_t)un * 64 + lane] = acc * di;
    } else {
      float v = fmaf(acc, di, b);
      v = fmaxf(v, 0.f);
      if (MODE == 1) v *= di;  // emit x' = dinv * relu(r)
      ((bf16*)outv)[(size_t)un * 64 + lane] = f2b(v);
    }
  }
}

// ---------- mean-pool (tower-merged): 64-node local accumulate, few atomics ----
__global__ __launch_bounds__(256) void k_pool(const float* __restrict__ x3,
                                              const int* __restrict__ batch1,
                                              const int* __restrict__ batch2,
                                              float* __restrict__ pooled1,
                                              float* __restrict__ cnt1,
                                              float* __restrict__ pooled2,
                                              float* __restrict__ cnt2, int n,
                                              int wpt) {
  int lane = threadIdx.x & 63;
  int wid = (blockIdx.x * blockDim.x + threadIdx.x) >> 6;
  int tower = wid >= wpt;
  int lw = wid - (tower ? wpt : 0);
  if (lw >= wpt) return;
  int beg = lw * POOL_CHUNK;
  if (beg >= n) return;
  int end = beg + POOL_CHUNK;
  if (end > n) end = n;
  const int* batch = tower ? batch2 : batch1;
  const float* x = x3 + (size_t)(tower ? n : 0) * 64;
  float* pooled = tower ? pooled2 : pooled1;
  float* cnt = tower ? cnt2 : cnt1;

  int cur = wave_uniform(batch[beg]);
  float acc = 0.f;
  int cl = 0;
  int i = beg;
  for (; i + 4 <= end; i += 4) {
    int g0 = wave_uniform(batch[i + 0]);
    int g3 = wave_uniform(batch[i + 3]);
    float a0 = x[(size_t)(i + 0) * 64 + lane];
    float a1 = x[(size_t)(i + 1) * 64 + lane];
    float a2 = x[(size_t)(i + 2) * 64 + lane];
    float a3 = x[(size_t)(i + 3) * 64 + lane];
    if (g0 == cur && g3 == cur) {
      acc += a0 + a1 + a2 + a3;
      cl += 4;
    } else {
      float av[4] = {a0, a1, a2, a3};
#pragma unroll
      for (int k = 0; k < 4; ++k) {
        int g = wave_uniform(batch[i + k]);
        if (g != cur) {
          atomicAdd(&pooled[cur * 64 + lane], acc);
          if (lane == 0) atomicAdd(&cnt[cur], (float)cl);
          acc = 0.f; cl = 0; cur = g;
        }
        acc += av[k];
        cl += 1;
      }
    }
  }
  for (; i < end; ++i) {
    int g = wave_uniform(batch[i]);
    float a = x[(size_t)i * 64 + lane];
    if (g != cur) {
      atomicAdd(&pooled[cur * 64 + lane], acc);
      if (lane == 0) atomicAdd(&cnt[cur], (float)cl);
      acc = 0.f; cl = 0; cur = g;
    }
    acc += a;
    cl += 1;
  }
  atomicAdd(&pooled[cur * 64 + lane], acc);
  if (lane == 0) atomicAdd(&cnt[cur], (float)cl);
}

// ---------- head: (mean t)@W3 + b3, then @Wlin + blin, L2 distance ----------
__global__ void k_final(const float* __restrict__ pooled1, const float* __restrict__ cnt1,
                        const float* __restrict__ pooled2, const float* __restrict__ cnt2,
                        const float* __restrict__ W3, const float* __restrict__ b3,
                        const float* __restrict__ Wlin, const float* __restrict__ blin,
                        float* __restrict__ outp) {
  int g = blockIdx.x;
  int lane = threadIdx.x;  // 64 threads
  float c1 = fmaxf(cnt1[g], 1.f), c2 = fmaxf(cnt2[g], 1.f);
  float p1 = pooled1[g * 64 + lane] / c1;
  float p2 = pooled2[g * 64 + lane] / c2;
  // stage 1: q = p @ W3 + b3
  float q1 = b3[lane], q2 = b3[lane];
  for (int j = 0; j < 64; ++j) {
    float w = W3[j * 64 + lane];
    q1 = fmaf(__shfl(p1, j), w, q1);
    q2 = fmaf(__shfl(p2, j), w, q2);
  }
  // stage 2: e = q @ Wlin + blin
  float e1 = blin[lane], e2 = blin[lane];
  for (int j = 0; j < 64; ++j) {
    float w = Wlin[j * 64 + lane];
    e1 = fmaf(__shfl(q1, j), w, e1);
    e2 = fmaf(__shfl(q2, j), w, e2);
  }
  float d = e1 - e2 + PD_EPS;
  float sq = d * d;
  for (int o = 32; o > 0; o >>= 1) sq += __shfl_down(sq, o);
  if (lane == 0) outp[g] = sqrtf(sq);
}

extern "C" void kernel_launch(void* const* d_in, const int* in_sizes, int n_in,
                              void* d_out, int out_size, void* d_ws, size_t ws_size,
                              hipStream_t stream) {
  const float* x1 = (const float*)d_in[0];
  const int* ei1 = (const int*)d_in[1];
  const int* batch1 = (const int*)d_in[2];
  const float* x2 = (const float*)d_in[3];
  const int* ei2 = (const int*)d_in[4];
  const int* batch2 = (const int*)d_in[5];
  const float* W1 = (const float*)d_in[6];
  const float* b1 = (const float*)d_in[7];
  const float* W2 = (const float*)d_in[8];
  const float* b2 = (const float*)d_in[9];
  const float* W3 = (const float*)d_in[10];
  const float* b3 = (const float*)d_in[11];
  const float* Wlin = (const float*)d_in[12];
  const float* blin = (const float*)d_in[13];

  const int N = in_sizes[2];      // 100000
  const int E = in_sizes[1] / 2;  // 1600000
  const int rng = (N + NCOLOR - 1) / NCOLOR;  // nodes per color (6250)
  const int nbN = (N + 255) / 256;            // 391
  const int Npad = nbN * 256;                 // 100096 (block-aligned segment)
  const int nb2 = 2 * nbN;                    // 782 scan blocks

  const int* src1 = ei1; const int* dst1 = ei1 + E;
  const int* src2 = ei2; const int* dst2 = ei2 + E;

  // workspace carve (~156 MB of >=268 MB)
  char* p = (char*)d_ws;
  auto alloc = [&](size_t bytes) {
    char* r = p;
    p += (bytes + 255) & ~(size_t)255;
    return r;
  };
  int* off = (int*)alloc((size_t)2 * (N + 1) * 4);
  int* cntn = (int*)alloc((size_t)2 * Npad * 4);
  int* bsums = (int*)alloc(1024 * 4);
  float* dinv = (float*)alloc((size_t)2 * N * 4);
  int* csr = (int*)alloc((size_t)2 * E * 4);
  ushort_t* partial1 = (ushort_t*)alloc((size_t)NCOLOR * KB * rng * 2);
  ushort_t* partial2 = (ushort_t*)alloc((size_t)NCOLOR * KB * rng * 2);
  bf16* hpA = (bf16*)alloc((size_t)2 * N * 64 * 2);
  bf16* hpB = (bf16*)alloc((size_t)2 * N * 64 * 2);
  float* bufF = (float*)alloc((size_t)2 * N * 64 * 4);
  // pooled1,cnt1,pooled2,cnt2 contiguous -> ONE memset covers all four
  float* pooled1 = (float*)alloc((size_t)NGRAPHS * 64 * 4);
  float* cnt1 = (float*)alloc((size_t)NGRAPHS * 4);
  float* pooled2 = (float*)alloc((size_t)NGRAPHS * 64 * 4);
  float* cnt2 = (float*)alloc((size_t)NGRAPHS * 4);
  size_t poolspan = (size_t)((char*)(cnt2 + NGRAPHS) - (char*)pooled1);

  const size_t ldsB = (size_t)rng * 4;  // 25 KB dynamic LDS -> 6 blocks/CU
  const int N2 = 2 * N;

  hipMemsetAsync(pooled1, 0, poolspan, stream);

  // CSR build, both towers in one pass each
  k_count_part<<<2 * NCOLOR * KB, 256, ldsB, stream>>>(dst1, dst2, partial1,
                                                       partial2, E, N, rng);
  k_reduce_part<<<nb2, 256, 0, stream>>>(partial1, partial2, cntn, dinv, N, Npad,
                                         rng);
  k_scan1<<<nb2, 256, 0, stream>>>(cntn, off, bsums, N, Npad);
  k_scan2<<<1, 1024, 0, stream>>>(bsums, nb2, nbN);
  k_off_final<<<nb2, 256, 0, stream>>>(off, bsums, N, Npad, E);
  k_fill_col<<<2 * NCOLOR * KB, 256, ldsB, stream>>>(src1, dst1, src2, dst2, off,
                                                     partial1, partial2, csr, E, N,
                                                     rng);

  // layer 1 (both towers)
  k_gemm_mfma<128, 1><<<1024, 256, 0, stream>>>(x1, x2, (const bf16*)nullptr, W1,
                                                dinv, hpA, N2, N);
  k_agg<0><<<4096, 256, 0, stream>>>(hpA, off, csr, dinv, b1, hpB, N2, N, E);
  // layer 2 (emits x' = dinv*relu(r2))
  k_gemm_mfma<64, 0><<<1024, 256, 0, stream>>>((const float*)nullptr,
                                               (const float*)nullptr, hpB, W2, dinv,
                                               hpA, N2, N);
  k_agg<1><<<4096, 256, 0, stream>>>(hpA, off, csr, dinv, b2, hpB, N2, N, E);
  // layer 3 folded (no W3): t = dinv*(x'_v + sum x'_u) -> f32 bufF
  k_agg<2><<<4096, 256, 0, stream>>>(hpB, off, csr, dinv, b3, bufF, N2, N, E);

  // mean-pool both towers in one dispatch (chunked local accumulate)
  const int wpt = (N + POOL_CHUNK - 1) / POOL_CHUNK;  // waves per tower
  const int poolBlocks = (2 * wpt + 3) / 4;
  k_pool<<<poolBlocks, 256, 0, stream>>>(bufF, batch1, batch2, pooled1, cnt1,
                                         pooled2, cnt2, N, wpt);

  k_final<<<NGRAPHS, 64, 0, stream>>>(pooled1, cnt1, pooled2, cnt2, W3, b3, Wlin,
                                      blin, (float*)d_out);
}